// Round 1
// baseline (548.660 us; speedup 1.0000x reference)
//
#include <hip/hip_runtime.h>

// Problem constants (fixed by reference setup_inputs)
namespace {
constexpr int Bn = 8, Cn = 64, On = 64, Hn = 112, Wn = 112;
constexpr int TH = 8, TW = 16;          // spatial tile per block
constexpr int CC = 8;                   // channel chunk
constexpr int NCH = Cn / CC;            // 8 chunks
constexpr int XROWS = TH + 2;           // 10 (halo)
constexpr int XCOLS = TW + 2;           // 18 (halo)
constexpr int XSTR = 20;                // padded LDS row stride (16B-aligned rows)
constexpr int WPAD = 68;                // padded oc stride (16B-aligned, 8-way max write conflict)
constexpr int HIST_N = Cn * 10;         // 640 hist entries
constexpr long CONV_ELEMS = (long)Bn * On * Hn * Wn;  // 6422528
}

// Setup: per-(c) weight-zero bookkeeping + zero the global hist region.
// n0[c]   = #oc whose 3x3 weights for channel c are all nonzero (normally 64)
// exCnt[c], exMask[c*64+e] = the rare oc with some exact-zero weight (9-bit mask)
__global__ void setup_kernel(const float* __restrict__ wt, float* __restrict__ hist,
                             int* __restrict__ n0, int* __restrict__ exCnt,
                             int* __restrict__ exMask) {
    int c = threadIdx.x;
    if (c >= Cn) return;
    int cnt0 = 0, ce = 0;
    for (int oc = 0; oc < On; ++oc) {
        unsigned m = 0;
        const float* wp = wt + (oc * Cn + c) * 9;
        for (int k = 0; k < 9; ++k)
            if (wp[k] == 0.0f) m |= (1u << k);
        if (m == 0u) ++cnt0;
        else exMask[c * 64 + (ce++)] = (int)m;
    }
    n0[c] = cnt0;
    exCnt[c] = ce;
    for (int j = 0; j < 10; ++j) hist[c * 10 + j] = 0.0f;
}

__global__ __launch_bounds__(256) void conv_hist_kernel(
    const float* __restrict__ x, const float* __restrict__ wt,
    const float* __restrict__ bias, float* __restrict__ out,
    float* __restrict__ hist, const int* __restrict__ n0,
    const int* __restrict__ exCnt, const int* __restrict__ exMask)
{
    __shared__ __align__(16) float xs[CC][XROWS][XSTR];   // 6400 B
    __shared__ __align__(16) float ws[CC][9][WPAD];       // 19584 B
    __shared__ unsigned hist_s[HIST_N];                   // 2560 B

    const int tid = threadIdx.x;
    const int bx = blockIdx.x;
    const int b  = bx / 98;              // 14*7 tiles per image
    const int tt = bx - b * 98;
    const int h0 = (tt / 7) * TH;
    const int w0 = (tt % 7) * TW;

    // conv mapping: thread = (ocg: 16 groups of 4 oc) x (pg: 16 pixel-groups of 8)
    const int ocg  = tid >> 4;           // 0..15
    const int pg   = tid & 15;           // 0..15
    const int prow = pg >> 1;            // 0..7
    const int pcol = (pg & 1) * 8;       // 0 or 8

    float acc[4][8];
#pragma unroll
    for (int o = 0; o < 4; ++o)
#pragma unroll
        for (int p = 0; p < 8; ++p) acc[o][p] = 0.0f;

    for (int i = tid; i < HIST_N; i += 256) hist_s[i] = 0u;

    for (int cc = 0; cc < NCH; ++cc) {
        const int cbase = cc * CC;
        __syncthreads();   // previous chunk's readers done (also covers hist_s zero-init)

        // ---- stage x tile (with zero halo) : 8*10*18 = 1440 elems ----
        for (int i = tid; i < CC * XROWS * XCOLS; i += 256) {
            int c  = i / (XROWS * XCOLS);
            int r  = (i - c * XROWS * XCOLS) / XCOLS;
            int cl = i - c * XROWS * XCOLS - r * XCOLS;
            int gr = h0 - 1 + r, gc = w0 - 1 + cl;
            float v = 0.0f;
            if ((unsigned)gr < (unsigned)Hn && (unsigned)gc < (unsigned)Wn)
                v = x[(((long)b * Cn + cbase + c) * Hn + gr) * Wn + gc];
            xs[c][r][cl] = v;
        }
        // ---- stage weights transposed to [c][k][oc] : 64*72 = 4608 elems ----
        // coalesced global read (k-minor), 8-way-conflict LDS write (tiny volume)
        for (int i = tid; i < On * CC * 9; i += 256) {
            int oc = i / (CC * 9);
            int j  = i - oc * (CC * 9);
            int c  = j / 9;
            int k  = j - c * 9;
            ws[c][k][oc] = wt[(oc * Cn + cbase + c) * 9 + k];
        }
        __syncthreads();

        // ---- conv compute ----
#pragma unroll
        for (int c = 0; c < CC; ++c) {
#pragma unroll
            for (int kh = 0; kh < 3; ++kh) {
                const float* xrow = &xs[c][prow + kh][pcol];
                float4 xa = *(const float4*)xrow;
                float4 xb = *(const float4*)(xrow + 4);
                float2 xc = *(const float2*)(xrow + 8);
                float xr[10] = {xa.x, xa.y, xa.z, xa.w,
                                xb.x, xb.y, xb.z, xb.w, xc.x, xc.y};
#pragma unroll
                for (int kw = 0; kw < 3; ++kw) {
                    float4 wv = *(const float4*)&ws[c][kh * 3 + kw][ocg * 4];
                    float wr[4] = {wv.x, wv.y, wv.z, wv.w};
#pragma unroll
                    for (int o = 0; o < 4; ++o)
#pragma unroll
                        for (int p = 0; p < 8; ++p)
                            acc[o][p] = fmaf(wr[o], xr[p + kw], acc[o][p]);
                }
            }
        }

        // ---- hist for this chunk: 8 channels x 16 row-groups of 8 px ----
        if (tid < CC * 16) {
            const int c   = tid >> 4;      // 0..7
            const int g   = tid & 15;
            const int hr  = g >> 1;        // 0..7
            const int hcb = (g & 1) * 8;
            unsigned rm[3];
#pragma unroll
            for (int kh = 0; kh < 3; ++kh) {
                const float* xrow = &xs[c][hr + kh][hcb];
                float4 xa = *(const float4*)xrow;
                float4 xb = *(const float4*)(xrow + 4);
                float2 xc = *(const float2*)(xrow + 8);
                unsigned m = 0;
                m |= (xa.x == 0.0f) ? 1u   : 0u;
                m |= (xa.y == 0.0f) ? 2u   : 0u;
                m |= (xa.z == 0.0f) ? 4u   : 0u;
                m |= (xa.w == 0.0f) ? 8u   : 0u;
                m |= (xb.x == 0.0f) ? 16u  : 0u;
                m |= (xb.y == 0.0f) ? 32u  : 0u;
                m |= (xb.z == 0.0f) ? 64u  : 0u;
                m |= (xb.w == 0.0f) ? 128u : 0u;
                m |= (xc.x == 0.0f) ? 256u : 0u;
                m |= (xc.y == 0.0f) ? 512u : 0u;
                rm[kh] = m;
            }
            const int cg = cbase + c;
            const unsigned inc = (unsigned)n0[cg];
            const int ec = exCnt[cg];
#pragma unroll
            for (int j = 0; j < 8; ++j) {
                unsigned m9 = ((rm[0] >> j) & 7u)
                            | (((rm[1] >> j) & 7u) << 3)
                            | (((rm[2] >> j) & 7u) << 6);
                atomicAdd(&hist_s[cg * 10 + __popc(m9)], inc);
                for (int e = 0; e < ec; ++e) {   // normally ec == 0
                    unsigned wz = (unsigned)exMask[cg * 64 + e];
                    atomicAdd(&hist_s[cg * 10 + __popc(m9 | wz)], 1u);
                }
            }
        }
    }

    // ---- conv epilogue: add bias, vector store ----
#pragma unroll
    for (int o = 0; o < 4; ++o) {
        const int oc = ocg * 4 + o;
        const float bv = bias[oc];
        float4 v0, v1;
        v0.x = acc[o][0] + bv; v0.y = acc[o][1] + bv;
        v0.z = acc[o][2] + bv; v0.w = acc[o][3] + bv;
        v1.x = acc[o][4] + bv; v1.y = acc[o][5] + bv;
        v1.z = acc[o][6] + bv; v1.w = acc[o][7] + bv;
        float* dst = &out[(((long)b * On + oc) * Hn + (h0 + prow)) * Wn + w0 + pcol];
        *(float4*)dst = v0;
        *(float4*)(dst + 4) = v1;
    }

    // ---- flush hist ----
    __syncthreads();
    for (int i = tid; i < HIST_N; i += 256)
        atomicAdd(&hist[i], (float)hist_s[i]);
}

extern "C" void kernel_launch(void* const* d_in, const int* in_sizes, int n_in,
                              void* d_out, int out_size, void* d_ws, size_t ws_size,
                              hipStream_t stream) {
    const float* x    = (const float*)d_in[0];
    const float* wt   = (const float*)d_in[1];
    const float* bias = (const float*)d_in[2];
    float* out  = (float*)d_out;
    float* hist = out + CONV_ELEMS;

    int* n0     = (int*)d_ws;
    int* exCnt  = n0 + 64;
    int* exMask = n0 + 128;       // 64*64 ints

    setup_kernel<<<1, 64, 0, stream>>>(wt, hist, n0, exCnt, exMask);

    const int nblocks = Bn * (Hn / TH) * (Wn / TW);   // 8*14*7 = 784
    conv_hist_kernel<<<nblocks, 256, 0, stream>>>(x, wt, bias, out, hist,
                                                  n0, exCnt, exMask);
}

// Round 2
// 174.136 us; speedup vs baseline: 3.1507x; 3.1507x over previous
//
#include <hip/hip_runtime.h>

// Problem constants (fixed by reference setup_inputs)
namespace {
constexpr int Bn = 8, Cn = 64, On = 64, Hn = 112, Wn = 112;
constexpr int TH = 8, TW = 16;          // spatial tile per block
constexpr int CC = 8;                   // channel chunk
constexpr int NCH = Cn / CC;            // 8 chunks
constexpr int XROWS = TH + 2;           // 10 (halo)
constexpr int XCOLS = TW + 2;           // 18 (halo)
constexpr int XSTR = 20;                // padded LDS row stride (16B-aligned rows)
constexpr int WPAD = 68;                // padded oc stride (16B-aligned)
constexpr int HIST_N = Cn * 10;         // 640 hist entries
constexpr long CONV_ELEMS = (long)Bn * On * Hn * Wn;  // 6422528
}

// Setup: per-(c) weight-zero bookkeeping + zero the global hist region.
__global__ void setup_kernel(const float* __restrict__ wt, float* __restrict__ hist,
                             int* __restrict__ n0, int* __restrict__ exCnt,
                             int* __restrict__ exMask) {
    int c = threadIdx.x;
    if (c >= Cn) return;
    int cnt0 = 0, ce = 0;
    for (int oc = 0; oc < On; ++oc) {
        unsigned m = 0;
        const float* wp = wt + (oc * Cn + c) * 9;
        for (int k = 0; k < 9; ++k)
            if (wp[k] == 0.0f) m |= (1u << k);
        if (m == 0u) ++cnt0;
        else exMask[c * 64 + (ce++)] = (int)m;
    }
    n0[c] = cnt0;
    exCnt[c] = ce;
    for (int j = 0; j < 10; ++j) hist[c * 10 + j] = 0.0f;
}

// __launch_bounds__(256, 4): cap VGPR at 128 -> 4 blocks/CU. Round-1 build
// hit 256 VGPR + ~870 MB of scratch spills (WRITE_SIZE 894 MB vs 26 MB ideal).
__global__ __launch_bounds__(256, 4) void conv_hist_kernel(
    const float* __restrict__ x, const float* __restrict__ wt,
    const float* __restrict__ bias, float* __restrict__ out,
    float* __restrict__ hist, const int* __restrict__ n0,
    const int* __restrict__ exCnt, const int* __restrict__ exMask)
{
    __shared__ __align__(16) float xs[CC][XROWS][XSTR];   // 6400 B
    __shared__ __align__(16) float ws[CC][9][WPAD];       // 19584 B
    __shared__ unsigned hist_s[HIST_N];                   // 2560 B

    const int tid = threadIdx.x;
    const int bx = blockIdx.x;
    const int b  = bx / 98;              // 14*7 tiles per image
    const int tt = bx - b * 98;
    const int h0 = (tt / 7) * TH;
    const int w0 = (tt % 7) * TW;

    // conv mapping: thread = (ocg: 16 groups of 4 oc) x (pg: 16 pixel-groups of 8)
    const int ocg  = tid >> 4;           // 0..15
    const int pg   = tid & 15;           // 0..15
    const int prow = pg >> 1;            // 0..7
    const int pcol = (pg & 1) * 8;       // 0 or 8

    float acc[4][8];
#pragma unroll
    for (int o = 0; o < 4; ++o)
#pragma unroll
        for (int p = 0; p < 8; ++p) acc[o][p] = 0.0f;

    for (int i = tid; i < HIST_N; i += 256) hist_s[i] = 0u;

#pragma unroll 1
    for (int cc = 0; cc < NCH; ++cc) {
        const int cbase = cc * CC;
        __syncthreads();   // previous chunk's readers done (also covers hist_s init)

        // ---- stage x tile (with zero halo) : 8*10*18 = 1440 elems ----
#pragma unroll 1
        for (int i = tid; i < CC * XROWS * XCOLS; i += 256) {
            int c  = i / (XROWS * XCOLS);
            int r  = (i - c * XROWS * XCOLS) / XCOLS;
            int cl = i - c * XROWS * XCOLS - r * XCOLS;
            int gr = h0 - 1 + r, gc = w0 - 1 + cl;
            float v = 0.0f;
            if ((unsigned)gr < (unsigned)Hn && (unsigned)gc < (unsigned)Wn)
                v = x[(((long)b * Cn + cbase + c) * Hn + gr) * Wn + gc];
            xs[c][r][cl] = v;
        }
        // ---- stage weights transposed to [c][k][oc] : 64*72 = 4608 elems ----
#pragma unroll 1
        for (int i = tid; i < On * CC * 9; i += 256) {
            int oc = i / (CC * 9);
            int j  = i - oc * (CC * 9);
            int c  = j / 9;
            int k  = j - c * 9;
            ws[c][k][oc] = wt[(oc * Cn + cbase + c) * 9 + k];
        }
        __syncthreads();

        // ---- conv compute: ONE channel at a time (unroll 1 -> ~80 live VGPRs,
        // round-1's full unroll hoisted 240 x + 288 w values and spilled) ----
#pragma unroll 1
        for (int c = 0; c < CC; ++c) {
#pragma unroll
            for (int kh = 0; kh < 3; ++kh) {
                const float* xrow = &xs[c][prow + kh][pcol];
                float4 xa = *(const float4*)xrow;
                float4 xb = *(const float4*)(xrow + 4);
                float2 xc = *(const float2*)(xrow + 8);
                float xr[10] = {xa.x, xa.y, xa.z, xa.w,
                                xb.x, xb.y, xb.z, xb.w, xc.x, xc.y};
#pragma unroll
                for (int kw = 0; kw < 3; ++kw) {
                    float4 wv = *(const float4*)&ws[c][kh * 3 + kw][ocg * 4];
                    float wr[4] = {wv.x, wv.y, wv.z, wv.w};
#pragma unroll
                    for (int o = 0; o < 4; ++o)
#pragma unroll
                        for (int p = 0; p < 8; ++p)
                            acc[o][p] = fmaf(wr[o], xr[p + kw], acc[o][p]);
                }
            }
        }

        // ---- hist for this chunk: 8 channels x 16 row-groups of 8 px ----
        if (tid < CC * 16) {
            const int c   = tid >> 4;      // 0..7
            const int g   = tid & 15;
            const int hr  = g >> 1;        // 0..7
            const int hcb = (g & 1) * 8;
            unsigned rm[3];
#pragma unroll
            for (int kh = 0; kh < 3; ++kh) {
                const float* xrow = &xs[c][hr + kh][hcb];
                float4 xa = *(const float4*)xrow;
                float4 xb = *(const float4*)(xrow + 4);
                float2 xc = *(const float2*)(xrow + 8);
                unsigned m = 0;
                m |= (xa.x == 0.0f) ? 1u   : 0u;
                m |= (xa.y == 0.0f) ? 2u   : 0u;
                m |= (xa.z == 0.0f) ? 4u   : 0u;
                m |= (xa.w == 0.0f) ? 8u   : 0u;
                m |= (xb.x == 0.0f) ? 16u  : 0u;
                m |= (xb.y == 0.0f) ? 32u  : 0u;
                m |= (xb.z == 0.0f) ? 64u  : 0u;
                m |= (xb.w == 0.0f) ? 128u : 0u;
                m |= (xc.x == 0.0f) ? 256u : 0u;
                m |= (xc.y == 0.0f) ? 512u : 0u;
                rm[kh] = m;
            }
            const int cg = cbase + c;
            const unsigned inc = (unsigned)n0[cg];
            const int ec = exCnt[cg];
#pragma unroll
            for (int j = 0; j < 8; ++j) {
                unsigned m9 = ((rm[0] >> j) & 7u)
                            | (((rm[1] >> j) & 7u) << 3)
                            | (((rm[2] >> j) & 7u) << 6);
                atomicAdd(&hist_s[cg * 10 + __popc(m9)], inc);
                for (int e = 0; e < ec; ++e) {   // normally ec == 0
                    unsigned wz = (unsigned)exMask[cg * 64 + e];
                    atomicAdd(&hist_s[cg * 10 + __popc(m9 | wz)], 1u);
                }
            }
        }
    }

    // ---- conv epilogue: add bias, vector store ----
#pragma unroll
    for (int o = 0; o < 4; ++o) {
        const int oc = ocg * 4 + o;
        const float bv = bias[oc];
        float4 v0, v1;
        v0.x = acc[o][0] + bv; v0.y = acc[o][1] + bv;
        v0.z = acc[o][2] + bv; v0.w = acc[o][3] + bv;
        v1.x = acc[o][4] + bv; v1.y = acc[o][5] + bv;
        v1.z = acc[o][6] + bv; v1.w = acc[o][7] + bv;
        float* dst = &out[(((long)b * On + oc) * Hn + (h0 + prow)) * Wn + w0 + pcol];
        *(float4*)dst = v0;
        *(float4*)(dst + 4) = v1;
    }

    // ---- flush hist ----
    __syncthreads();
    for (int i = tid; i < HIST_N; i += 256)
        atomicAdd(&hist[i], (float)hist_s[i]);
}

extern "C" void kernel_launch(void* const* d_in, const int* in_sizes, int n_in,
                              void* d_out, int out_size, void* d_ws, size_t ws_size,
                              hipStream_t stream) {
    const float* x    = (const float*)d_in[0];
    const float* wt   = (const float*)d_in[1];
    const float* bias = (const float*)d_in[2];
    float* out  = (float*)d_out;
    float* hist = out + CONV_ELEMS;

    int* n0     = (int*)d_ws;
    int* exCnt  = n0 + 64;
    int* exMask = n0 + 128;       // 64*64 ints

    setup_kernel<<<1, 64, 0, stream>>>(wt, hist, n0, exCnt, exMask);

    const int nblocks = Bn * (Hn / TH) * (Wn / TW);   // 8*14*7 = 784
    conv_hist_kernel<<<nblocks, 256, 0, stream>>>(x, wt, bias, out, hist,
                                                  n0, exCnt, exMask);
}

// Round 3
// 165.830 us; speedup vs baseline: 3.3086x; 1.0501x over previous
//
#include <hip/hip_runtime.h>

typedef __attribute__((ext_vector_type(8))) short bf16x8;
typedef __attribute__((ext_vector_type(4))) float f32x4;
typedef __attribute__((ext_vector_type(4))) unsigned u32x4;

namespace {
constexpr int Bn = 8, Cn = 64, On = 64, Hn = 112, Wn = 112;
constexpr long CONV_ELEMS = (long)Bn * On * Hn * Wn;   // 6422528
constexpr int HP = 114, WP = 114;                      // padded (halo) dims
constexpr long XT_ELEMS = (long)Bn * HP * WP * Cn;     // 6,653,952
constexpr int WB_PER_OC = 1152;                        // hi(576) + lo(576)
constexpr size_t META_BYTES = 17408;                   // n0,exCnt,exMask,exTot (padded)
constexpr size_t XH_BYTES = (size_t)XT_ELEMS * 2;      // 13,307,904
constexpr size_t NEED_WS = META_BYTES + 2 * XH_BYTES + (size_t)On * WB_PER_OC * 2;
constexpr int HIST_N = Cn * 10;
}

__device__ __forceinline__ ushort f2bf(float v) {      // RNE float->bf16 bits
    unsigned u = __float_as_uint(v);
    return (ushort)((u + 0x7fffu + ((u >> 16) & 1u)) >> 16);
}
__device__ __forceinline__ float bf2f(ushort b) {
    return __uint_as_float(((unsigned)b) << 16);
}

// ---------------- setup: weight-zero bookkeeping + zero hist ----------------
__global__ void setup_kernel(const float* __restrict__ wt, float* __restrict__ hist,
                             int* __restrict__ n0, int* __restrict__ exCnt,
                             int* __restrict__ exMask, int* __restrict__ exTot) {
    int c = threadIdx.x;
    if (c < Cn) {
        int cnt0 = 0, ce = 0;
        for (int oc = 0; oc < On; ++oc) {
            unsigned m = 0;
            const float* wp = wt + (oc * Cn + c) * 9;
            for (int k = 0; k < 9; ++k)
                if (wp[k] == 0.0f) m |= (1u << k);
            if (m == 0u) ++cnt0;
            else exMask[c * 64 + (ce++)] = (int)m;
        }
        n0[c] = cnt0;
        exCnt[c] = ce;
        for (int j = 0; j < 10; ++j) hist[c * 10 + j] = 0.0f;
    }
    __syncthreads();
    if (threadIdx.x == 0) {
        int s = 0;
        for (int i = 0; i < Cn; ++i) s += exCnt[i];
        exTot[0] = s;
    }
}

// ---------------- MFMA path: prep kernels ----------------
__global__ void zero_ws_kernel(uint4* __restrict__ p, long n16) {
    long i = (long)blockIdx.x * blockDim.x + threadIdx.x;
    long stride = (long)gridDim.x * blockDim.x;
    uint4 z = {0u, 0u, 0u, 0u};
    for (; i < n16; i += stride) p[i] = z;
}

// wb[oc][k], k = kp*64 + c ; hi at [0,576), lo at [576,1152)
__global__ void prep_w_kernel(const float* __restrict__ wt, ushort* __restrict__ wb) {
    const int oc = blockIdx.x;
    for (int i = threadIdx.x; i < 576; i += blockDim.x) {
        int kp = i >> 6, c = i & 63;
        float v = wt[(oc * Cn + c) * 9 + kp];
        ushort hi = f2bf(v);
        ushort lo = f2bf(v - bf2f(hi));
        wb[oc * WB_PER_OC + i] = hi;
        wb[oc * WB_PER_OC + 576 + i] = lo;
    }
}

// x (NCHW fp32) -> xh/xl [b][h+1][w+1][c] bf16, interior only (halo pre-zeroed)
__global__ __launch_bounds__(256) void prep_x_kernel(
    const float* __restrict__ x, ushort* __restrict__ xh, ushort* __restrict__ xl) {
    __shared__ float ls[64][57];
    const int bx = blockIdx.x;            // 8 * 112 * 2
    const int b = bx / 224;
    const int rem = bx - b * 224;
    const int h = rem >> 1;
    const int w0 = (rem & 1) * 56;
    const int tid = threadIdx.x;
    for (int i = tid; i < 64 * 56; i += 256) {
        int c = i / 56, w = i - c * 56;
        ls[c][w] = x[(((long)b * Cn + c) * Hn + h) * Wn + w0 + w];
    }
    __syncthreads();
    for (int i = tid; i < 56 * 64; i += 256) {
        int w = i >> 6, c = i & 63;
        float v = ls[c][w];
        ushort hi = f2bf(v);
        ushort lo = f2bf(v - bf2f(hi));
        long idx = (((long)b * HP + h + 1) * WP + (w0 + w + 1)) * 64 + c;
        xh[idx] = hi;
        xl[idx] = lo;
    }
}

// ---------------- MFMA main kernel: conv + fused hist ----------------
// Grid 392 = 8b * 7 * 7 tiles of 16x16 px. 4 waves/block, each wave: 64px x 64oc.
// K = 3 segments x 576 (x_hi*w_hi + x_hi*w_lo + x_lo*w_hi).
__global__ __launch_bounds__(256) void conv_mfma_kernel(
    const ushort* __restrict__ xh, const ushort* __restrict__ xl,
    const ushort* __restrict__ wb, const float* __restrict__ bias,
    float* __restrict__ out, float* __restrict__ hist, const int* __restrict__ n0)
{
    __shared__ unsigned hist_s[HIST_N];
    __shared__ int n0s[Cn];
    const int tid = threadIdx.x;
    for (int i = tid; i < HIST_N; i += 256) hist_s[i] = 0u;
    if (tid < Cn) n0s[tid] = n0[tid];
    __syncthreads();

    const int bx = blockIdx.x;
    const int b = bx / 49;
    const int t = bx - b * 49;
    const int h0 = (t / 7) * 16, w0 = (t % 7) * 16;
    const int lane = tid & 63, wv = tid >> 6;
    const int l15 = lane & 15, lg = lane >> 4;

    f32x4 acc[4][4];
#pragma unroll
    for (int a = 0; a < 4; ++a)
#pragma unroll
        for (int g = 0; g < 4; ++g) acc[a][g] = (f32x4){0.f, 0.f, 0.f, 0.f};

    unsigned cnt0[4] = {0, 0, 0, 0};   // nibble zero-counters, c-half 0
    unsigned cnt1[4] = {0, 0, 0, 0};   // c-half 1

    const int Abase = (((b * HP) + h0 + 4 * wv) * WP + w0 + l15) * 64 + 8 * lg;
    int boff[4];
#pragma unroll
    for (int g = 0; g < 4; ++g) boff[g] = (g * 16 + l15) * WB_PER_OC + 8 * lg;

    bf16x8 A0[4], B0[4], A1[4], B1[4];

#pragma unroll 1
    for (int seg = 0; seg < 3; ++seg) {
        const ushort* As = (seg == 2 ? xl : xh) + Abase;
        const int koff = (seg == 1) ? 576 : 0;

        auto loadA = [&](int k, bf16x8* A) {
            int kp = k >> 1, ch = k & 1;
            int dh = kp / 3, dw = kp - 3 * dh;
            int off = (dh * WP + dw) * 64 + 32 * ch;
#pragma unroll
            for (int a = 0; a < 4; ++a)
                A[a] = *(const bf16x8*)(As + off + a * (WP * 64));
        };
        auto loadB = [&](int k, bf16x8* Bv) {
            int kk = koff + k * 32;
#pragma unroll
            for (int g = 0; g < 4; ++g)
                Bv[g] = *(const bf16x8*)(wb + boff[g] + kk);
        };

        loadA(0, A0); loadB(0, B0);
#pragma unroll 1
        for (int ki = 0; ki < 18; ki += 2) {
            loadA(ki + 1, A1); loadB(ki + 1, B1);
            if (seg == 0) {
#pragma unroll
                for (int a = 0; a < 4; ++a) {
                    u32x4 u = __builtin_bit_cast(u32x4, A0[a]);
                    unsigned inc = 0;
#pragma unroll
                    for (int r = 0; r < 4; ++r) {
                        unsigned w = u[r];
                        inc += ((w & 0xffffu) == 0u) ? (1u << (8 * r)) : 0u;
                        inc += ((w >> 16) == 0u) ? (1u << (8 * r + 4)) : 0u;
                    }
                    cnt0[a] += inc;
                }
            }
#pragma unroll
            for (int a = 0; a < 4; ++a)
#pragma unroll
                for (int g = 0; g < 4; ++g)
                    acc[a][g] = __builtin_amdgcn_mfma_f32_16x16x32_bf16(
                        A0[a], B0[g], acc[a][g], 0, 0, 0);

            int k2 = (ki + 2 < 18) ? (ki + 2) : 17;   // clamped redundant prefetch
            loadA(k2, A0); loadB(k2, B0);
            if (seg == 0) {
#pragma unroll
                for (int a = 0; a < 4; ++a) {
                    u32x4 u = __builtin_bit_cast(u32x4, A1[a]);
                    unsigned inc = 0;
#pragma unroll
                    for (int r = 0; r < 4; ++r) {
                        unsigned w = u[r];
                        inc += ((w & 0xffffu) == 0u) ? (1u << (8 * r)) : 0u;
                        inc += ((w >> 16) == 0u) ? (1u << (8 * r + 4)) : 0u;
                    }
                    cnt1[a] += inc;
                }
            }
#pragma unroll
            for (int a = 0; a < 4; ++a)
#pragma unroll
                for (int g = 0; g < 4; ++g)
                    acc[a][g] = __builtin_amdgcn_mfma_f32_16x16x32_bf16(
                        A1[a], B1[g], acc[a][g], 0, 0, 0);
        }
    }

    // conv store: D mapping col=lane&15 (oc), row=(lane>>4)*4+reg (w-offset)
#pragma unroll
    for (int g = 0; g < 4; ++g) {
        const int oc = g * 16 + l15;
        const float bv = bias[oc];
#pragma unroll
        for (int a = 0; a < 4; ++a) {
            const int hr = h0 + 4 * wv + a;
            float4 st = {acc[a][g].x + bv, acc[a][g].y + bv,
                         acc[a][g].z + bv, acc[a][g].w + bv};
            *reinterpret_cast<float4*>(
                out + (((long)b * On + oc) * Hn + hr) * Wn + w0 + lg * 4) = st;
        }
    }

    // hist flush: lane owns (px = (a, l15), channels 8*lg+j + 32*ch)
#pragma unroll
    for (int a = 0; a < 4; ++a) {
#pragma unroll
        for (int ch = 0; ch < 2; ++ch) {
            unsigned v = ch ? cnt1[a] : cnt0[a];
#pragma unroll
            for (int j = 0; j < 8; ++j) {
                int c = 32 * ch + 8 * lg + j;
                int bin = (v >> (4 * j)) & 15;
                atomicAdd(&hist_s[c * 10 + bin], (unsigned)n0s[c]);
            }
        }
    }
    __syncthreads();
    for (int i = tid; i < HIST_N; i += 256)
        atomicAdd(&hist[i], (float)hist_s[i]);
}

// Exact-zero-weight correction (never taken for Gaussian weights; kept for strict
// faithfulness to the reference semantics).
__global__ void correction_kernel(const float* __restrict__ x, float* __restrict__ hist,
                                  const int* __restrict__ exCnt,
                                  const int* __restrict__ exMask,
                                  const int* __restrict__ exTot) {
    const int c = blockIdx.x;
    if (exTot[0] == 0 || exCnt[c] == 0) return;
    const int ec = exCnt[c];
    for (long p = threadIdx.x; p < (long)Bn * Hn * Wn; p += blockDim.x) {
        int b = (int)(p / (Hn * Wn));
        int r = (int)((p / Wn) % Hn);
        int w = (int)(p % Wn);
        unsigned m9 = 0;
        int bit = 0;
        for (int kh = 0; kh < 3; ++kh)
            for (int kw = 0; kw < 3; ++kw, ++bit) {
                int rr = r + kh - 1, ww = w + kw - 1;
                float v = 0.f;
                if ((unsigned)rr < (unsigned)Hn && (unsigned)ww < (unsigned)Wn)
                    v = x[(((long)b * Cn + c) * Hn + rr) * Wn + ww];
                if (v == 0.f) m9 |= 1u << bit;
            }
        for (int e = 0; e < ec; ++e)
            atomicAdd(&hist[c * 10 + __popc(m9 | (unsigned)exMask[c * 64 + e])], 1.0f);
    }
}

// ---------------- fallback: round-2 fp32 kernel (used if ws too small) ----------------
namespace fb {
constexpr int TH = 8, TW = 16, CC = 8, NCH = Cn / CC;
constexpr int XROWS = TH + 2, XCOLS = TW + 2, XSTR = 20, WPAD = 68;
}
__global__ __launch_bounds__(256, 4) void conv_hist_kernel(
    const float* __restrict__ x, const float* __restrict__ wt,
    const float* __restrict__ bias, float* __restrict__ out,
    float* __restrict__ hist, const int* __restrict__ n0,
    const int* __restrict__ exCnt, const int* __restrict__ exMask)
{
    using namespace fb;
    __shared__ __align__(16) float xs[CC][XROWS][XSTR];
    __shared__ __align__(16) float ws[CC][9][WPAD];
    __shared__ unsigned hist_s[HIST_N];
    const int tid = threadIdx.x;
    const int bx = blockIdx.x;
    const int b = bx / 98;
    const int tt = bx - b * 98;
    const int h0 = (tt / 7) * TH;
    const int w0 = (tt % 7) * TW;
    const int ocg = tid >> 4, pg = tid & 15;
    const int prow = pg >> 1, pcol = (pg & 1) * 8;
    float acc[4][8];
#pragma unroll
    for (int o = 0; o < 4; ++o)
#pragma unroll
        for (int p = 0; p < 8; ++p) acc[o][p] = 0.0f;
    for (int i = tid; i < HIST_N; i += 256) hist_s[i] = 0u;
#pragma unroll 1
    for (int cc = 0; cc < NCH; ++cc) {
        const int cbase = cc * CC;
        __syncthreads();
#pragma unroll 1
        for (int i = tid; i < CC * XROWS * XCOLS; i += 256) {
            int c = i / (XROWS * XCOLS);
            int r = (i - c * XROWS * XCOLS) / XCOLS;
            int cl = i - c * XROWS * XCOLS - r * XCOLS;
            int gr = h0 - 1 + r, gc = w0 - 1 + cl;
            float v = 0.0f;
            if ((unsigned)gr < (unsigned)Hn && (unsigned)gc < (unsigned)Wn)
                v = x[(((long)b * Cn + cbase + c) * Hn + gr) * Wn + gc];
            xs[c][r][cl] = v;
        }
#pragma unroll 1
        for (int i = tid; i < On * CC * 9; i += 256) {
            int oc = i / (CC * 9);
            int j = i - oc * (CC * 9);
            int c = j / 9;
            int k = j - c * 9;
            ws[c][k][oc] = wt[(oc * Cn + cbase + c) * 9 + k];
        }
        __syncthreads();
#pragma unroll 1
        for (int c = 0; c < CC; ++c) {
#pragma unroll
            for (int kh = 0; kh < 3; ++kh) {
                const float* xrow = &xs[c][prow + kh][pcol];
                float4 xa = *(const float4*)xrow;
                float4 xb = *(const float4*)(xrow + 4);
                float2 xc = *(const float2*)(xrow + 8);
                float xr[10] = {xa.x, xa.y, xa.z, xa.w,
                                xb.x, xb.y, xb.z, xb.w, xc.x, xc.y};
#pragma unroll
                for (int kw = 0; kw < 3; ++kw) {
                    float4 wv = *(const float4*)&ws[c][kh * 3 + kw][ocg * 4];
                    float wr[4] = {wv.x, wv.y, wv.z, wv.w};
#pragma unroll
                    for (int o = 0; o < 4; ++o)
#pragma unroll
                        for (int p = 0; p < 8; ++p)
                            acc[o][p] = fmaf(wr[o], xr[p + kw], acc[o][p]);
                }
            }
        }
        if (tid < CC * 16) {
            const int c = tid >> 4;
            const int g = tid & 15;
            const int hr = g >> 1;
            const int hcb = (g & 1) * 8;
            unsigned rm[3];
#pragma unroll
            for (int kh = 0; kh < 3; ++kh) {
                const float* xrow = &xs[c][hr + kh][hcb];
                float4 xa = *(const float4*)xrow;
                float4 xb = *(const float4*)(xrow + 4);
                float2 xc = *(const float2*)(xrow + 8);
                unsigned m = 0;
                m |= (xa.x == 0.0f) ? 1u : 0u;
                m |= (xa.y == 0.0f) ? 2u : 0u;
                m |= (xa.z == 0.0f) ? 4u : 0u;
                m |= (xa.w == 0.0f) ? 8u : 0u;
                m |= (xb.x == 0.0f) ? 16u : 0u;
                m |= (xb.y == 0.0f) ? 32u : 0u;
                m |= (xb.z == 0.0f) ? 64u : 0u;
                m |= (xb.w == 0.0f) ? 128u : 0u;
                m |= (xc.x == 0.0f) ? 256u : 0u;
                m |= (xc.y == 0.0f) ? 512u : 0u;
                rm[kh] = m;
            }
            const int cg = cbase + c;
            const unsigned inc = (unsigned)n0[cg];
            const int ec = exCnt[cg];
#pragma unroll
            for (int j = 0; j < 8; ++j) {
                unsigned m9 = ((rm[0] >> j) & 7u)
                            | (((rm[1] >> j) & 7u) << 3)
                            | (((rm[2] >> j) & 7u) << 6);
                atomicAdd(&hist_s[cg * 10 + __popc(m9)], inc);
                for (int e = 0; e < ec; ++e) {
                    unsigned wz = (unsigned)exMask[cg * 64 + e];
                    atomicAdd(&hist_s[cg * 10 + __popc(m9 | wz)], 1u);
                }
            }
        }
    }
#pragma unroll
    for (int o = 0; o < 4; ++o) {
        const int oc = ocg * 4 + o;
        const float bv = bias[oc];
        float4 v0, v1;
        v0.x = acc[o][0] + bv; v0.y = acc[o][1] + bv;
        v0.z = acc[o][2] + bv; v0.w = acc[o][3] + bv;
        v1.x = acc[o][4] + bv; v1.y = acc[o][5] + bv;
        v1.z = acc[o][6] + bv; v1.w = acc[o][7] + bv;
        float* dst = &out[(((long)b * On + oc) * Hn + (h0 + prow)) * Wn + w0 + pcol];
        *(float4*)dst = v0;
        *(float4*)(dst + 4) = v1;
    }
    __syncthreads();
    for (int i = tid; i < HIST_N; i += 256)
        atomicAdd(&hist[i], (float)hist_s[i]);
}

// ---------------- host ----------------
extern "C" void kernel_launch(void* const* d_in, const int* in_sizes, int n_in,
                              void* d_out, int out_size, void* d_ws, size_t ws_size,
                              hipStream_t stream) {
    const float* x    = (const float*)d_in[0];
    const float* wt   = (const float*)d_in[1];
    const float* bias = (const float*)d_in[2];
    float* out  = (float*)d_out;
    float* hist = out + CONV_ELEMS;

    int* n0     = (int*)d_ws;
    int* exCnt  = n0 + 64;
    int* exMask = n0 + 128;          // 64*64 ints
    int* exTot  = n0 + 128 + 4096;

    setup_kernel<<<1, 64, 0, stream>>>(wt, hist, n0, exCnt, exMask, exTot);

    if (ws_size >= NEED_WS) {
        ushort* xh = (ushort*)((char*)d_ws + META_BYTES);
        ushort* xl = xh + XT_ELEMS;
        ushort* wb = xl + XT_ELEMS;

        zero_ws_kernel<<<2048, 256, 0, stream>>>((uint4*)xh, (long)(2 * XH_BYTES / 16));
        prep_w_kernel<<<On, 256, 0, stream>>>(wt, wb);
        prep_x_kernel<<<Bn * Hn * 2, 256, 0, stream>>>(x, xh, xl);
        conv_mfma_kernel<<<Bn * 7 * 7, 256, 0, stream>>>(xh, xl, wb, bias, out, hist, n0);
        correction_kernel<<<Cn, 256, 0, stream>>>(x, hist, exCnt, exMask, exTot);
    } else {
        conv_hist_kernel<<<Bn * 14 * 7, 256, 0, stream>>>(x, wt, bias, out, hist,
                                                          n0, exCnt, exMask);
    }
}

// Round 4
// 141.559 us; speedup vs baseline: 3.8758x; 1.1715x over previous
//
#include <hip/hip_runtime.h>

typedef __attribute__((ext_vector_type(8))) short bf16x8;
typedef __attribute__((ext_vector_type(4))) float f32x4;

namespace {
constexpr int Bn = 8, Cn = 64, On = 64, Hn = 112, Wn = 112;
constexpr long CONV_ELEMS = (long)Bn * On * Hn * Wn;     // 6422528
constexpr int HP = 114, WP = 114;                        // padded dims (halo)
constexpr long XT_ELEMS = (long)Bn * HP * WP * Cn;       // 6653952
constexpr int WB_PER_OC = 1152;                          // hi 576 + lo 576
constexpr size_t META_BYTES = 17408;
constexpr size_t NEED_WS = META_BYTES + (size_t)XT_ELEMS * 2 + (size_t)On * WB_PER_OC * 2;
constexpr int HIST_N = Cn * 10;
constexpr int HALO_PER_B = 2 * WP * Cn + 2 * Hn * Cn;    // 28928
constexpr int HALO_ELEMS = Bn * HALO_PER_B;              // 231424
constexpr int INT_BLOCKS = Bn * Hn * 2;                  // 1792
constexpr int HALO_BLOCKS = (HALO_ELEMS + 255) / 256;    // 904
}

__device__ __forceinline__ ushort f2bf(float v) {        // RNE float->bf16 bits
    unsigned u = __float_as_uint(v);
    return (ushort)((u + 0x7fffu + ((u >> 16) & 1u)) >> 16);
}
__device__ __forceinline__ float bf2f(ushort b) {
    return __uint_as_float(((unsigned)b) << 16);
}

// ---- weights -> wb[oc][k] (k = kp*64+c), hi|lo; zero-weight bookkeeping; hist zero ----
__global__ void prep_wsetup_kernel(const float* __restrict__ wt, ushort* __restrict__ wb,
                                   float* __restrict__ hist, int* __restrict__ n0,
                                   int* __restrict__ exCnt, int* __restrict__ exMask) {
    __shared__ int ecnt;
    const int c = blockIdx.x;      // 64 blocks
    const int oc = threadIdx.x;    // 64 threads = 1 wave
    if (oc == 0) ecnt = 0;
    __syncthreads();
    const float* wp = wt + (oc * Cn + c) * 9;
    unsigned m = 0;
    float wv[9];
#pragma unroll
    for (int k = 0; k < 9; ++k) {
        wv[k] = wp[k];
        if (wv[k] == 0.0f) m |= 1u << k;
    }
#pragma unroll
    for (int kp = 0; kp < 9; ++kp) {
        ushort hi = f2bf(wv[kp]);
        ushort lo = f2bf(wv[kp] - bf2f(hi));
        wb[oc * WB_PER_OC + kp * 64 + c] = hi;
        wb[oc * WB_PER_OC + 576 + kp * 64 + c] = lo;
    }
    unsigned long long zb = __ballot(m == 0u);
    if (m != 0u) {
        int slot = atomicAdd(&ecnt, 1);
        exMask[c * 64 + slot] = (int)m;
    }
    __syncthreads();
    if (oc == 0) { n0[c] = __popcll(zb); exCnt[c] = ecnt; }
    if (c == 0) for (int i = oc; i < HIST_N; i += 64) hist[i] = 0.0f;
}

// ---- x (NCHW fp32) -> xh [b][h+1][w+1][c] bf16; halo-zero fused via extra blocks ----
__global__ __launch_bounds__(256) void prep_x_kernel(
    const float* __restrict__ x, ushort* __restrict__ xh) {
    const int bx = blockIdx.x;
    const int tid = threadIdx.x;
    if (bx >= INT_BLOCKS) {                       // halo-zero blocks
        int idx = (bx - INT_BLOCKS) * 256 + tid;
        if (idx < HALO_ELEMS) {
            int b = idx / HALO_PER_B;
            int r = idx - b * HALO_PER_B;
            int h, w, cc;
            if (r < WP * Cn)                    { h = 0;      w = r / Cn;               cc = r & 63; }
            else if (r < 2 * WP * Cn)           { int q = r - WP * Cn; h = HP - 1; w = q / Cn; cc = q & 63; }
            else if (r < 2 * WP * Cn + Hn * Cn) { int q = r - 2 * WP * Cn; h = 1 + q / Cn; w = 0; cc = q & 63; }
            else                                { int q = r - 2 * WP * Cn - Hn * Cn; h = 1 + q / Cn; w = WP - 1; cc = q & 63; }
            xh[((long)(b * HP + h) * WP + w) * 64 + cc] = 0;
        }
        return;
    }
    __shared__ float ls[64][57];
    const int b = bx / 224;
    const int rem = bx - b * 224;
    const int h = rem >> 1;
    const int w0 = (rem & 1) * 56;
    for (int i = tid; i < 64 * 56; i += 256) {
        int c = i / 56, w = i - c * 56;
        ls[c][w] = x[(((long)b * Cn + c) * Hn + h) * Wn + w0 + w];
    }
    __syncthreads();
    for (int i = tid; i < 56 * 64; i += 256) {
        int w = i >> 6, c = i & 63;
        xh[(((long)b * HP + h + 1) * WP + (w0 + w + 1)) * 64 + c] = f2bf(ls[c][w]);
    }
}

// ---- hist: per-(b,c) plane, row zero-masks + 3-row popc windows, reg-packed bins ----
__global__ __launch_bounds__(256) void hist_kernel(
    const float* __restrict__ x, float* __restrict__ hist, const int* __restrict__ n0) {
    __shared__ float xs[Hn * 113];                // stride 113 -> conflict-free column reads
    __shared__ unsigned long long zr[HP][2];      // 114-bit row masks, rows -1..112
    __shared__ unsigned hcnt[10];
    const int tid = threadIdx.x;
    const int b = blockIdx.x >> 6;
    const int c = blockIdx.x & 63;
    if (tid < 10) hcnt[tid] = 0u;
    const float* xp = x + ((long)b * Cn + c) * (Hn * Wn);
    for (int i = tid; i < Hn * Wn; i += 256) {
        int r = i / Wn, w = i - r * Wn;
        xs[r * 113 + w] = xp[i];
    }
    if (tid < 2) { zr[tid * (HP - 1)][0] = ~0ull; zr[tid * (HP - 1)][1] = ~0ull; }
    __syncthreads();
    if (tid < Hn) {                               // build row mask: bit j = (col j-1 == 0)
        const int r = tid;
        unsigned long long m0 = 1ull, m1 = 1ull << 49;   // padding cols -1, 112
        for (int w = 0; w < Wn; ++w) {
            unsigned long long z = (xs[r * 113 + w] == 0.0f) ? 1ull : 0ull;
            int bitp = w + 1;
            if (bitp < 64) m0 |= z << bitp; else m1 |= z << (bitp - 64);
        }
        zr[r + 1][0] = m0; zr[r + 1][1] = m1;
    }
    __syncthreads();
    if (tid < 224) {                              // 2 threads per row, 56 px each
        const int r = tid >> 1, half = tid & 1;
        unsigned long long t0 = zr[r][0],     t1 = zr[r][1];
        unsigned long long m0 = zr[r + 1][0], m1 = zr[r + 1][1];
        unsigned long long b0 = zr[r + 2][0], b1 = zr[r + 2][1];
        unsigned long long T, M, B2;
        if (half == 0) { T = t0; M = m0; B2 = b0; }
        else { T = (t0 >> 56) | (t1 << 8); M = (m0 >> 56) | (m1 << 8); B2 = (b0 >> 56) | (b1 << 8); }
        unsigned pk0 = 0, pk1 = 0;                // bins 0..4 / 5..9, 6 bits each (max 56)
        for (int w = 0; w < 56; ++w) {
            int z = __popc((unsigned)(T >> w) & 7u) + __popc((unsigned)(M >> w) & 7u)
                  + __popc((unsigned)(B2 >> w) & 7u);
            if (z < 5) pk0 += 1u << (6 * z); else pk1 += 1u << (6 * (z - 5));
        }
#pragma unroll
        for (int j = 0; j < 5; ++j) {
            atomicAdd(&hcnt[j],     (pk0 >> (6 * j)) & 63u);
            atomicAdd(&hcnt[5 + j], (pk1 >> (6 * j)) & 63u);
        }
    }
    __syncthreads();
    if (tid < 10)
        atomicAdd(&hist[c * 10 + tid], (float)(hcnt[tid] * (unsigned)n0[c]));
}

// ---- conv: wave = 32px x 64oc, K=1152 (w hi+lo share A-frags), no LDS, no barriers ----
__global__ __launch_bounds__(256, 3) void conv_mfma_kernel(
    const ushort* __restrict__ xh, const ushort* __restrict__ wb,
    const float* __restrict__ bias, float* __restrict__ out)
{
    int bid = (int)blockIdx.x;
    bid = (bid & 7) * 98 + (bid >> 3);            // XCD swizzle: one image per XCD
    const int b = bid / 98;
    const int t = bid - b * 98;
    const int h0 = (t / 7) * 8, w0 = (t % 7) * 16;
    const int tid = threadIdx.x;
    const int lane = tid & 63, wvi = tid >> 6;
    const int l15 = lane & 15, lg = lane >> 4;

    f32x4 acc[2][4];
#pragma unroll
    for (int a = 0; a < 2; ++a)
#pragma unroll
        for (int g = 0; g < 4; ++g) acc[a][g] = (f32x4){0.f, 0.f, 0.f, 0.f};

    const ushort* As = xh + ((long)((b * HP + h0 + 2 * wvi) * WP + w0 + l15) * 64 + 8 * lg);
    const ushort* Bs = wb + 8 * lg;
    int boff[4];
#pragma unroll
    for (int g = 0; g < 4; ++g) boff[g] = (g * 16 + l15) * WB_PER_OC;

    bf16x8 A0[2], A1[2], BH0[4], BL0[4], BH1[4], BL1[4];

    auto loadA = [&](int k, bf16x8* A) {
        int kp = k >> 1, ch = k & 1;
        int dh = kp / 3, dw = kp - 3 * dh;
        int off = (dh * WP + dw) * 64 + 32 * ch;
#pragma unroll
        for (int a = 0; a < 2; ++a)
            A[a] = *(const bf16x8*)(As + off + a * (WP * 64));
    };
    auto loadB = [&](int k, bf16x8* BH, bf16x8* BL) {
        int kk = k * 32;
#pragma unroll
        for (int g = 0; g < 4; ++g) {
            BH[g] = *(const bf16x8*)(Bs + boff[g] + kk);
            BL[g] = *(const bf16x8*)(Bs + boff[g] + 576 + kk);
        }
    };

    loadA(0, A0); loadB(0, BH0, BL0);
    loadA(1, A1); loadB(1, BH1, BL1);

#pragma unroll 1
    for (int k = 0; k < 18; k += 2) {
#pragma unroll
        for (int a = 0; a < 2; ++a)
#pragma unroll
            for (int g = 0; g < 4; ++g)
                acc[a][g] = __builtin_amdgcn_mfma_f32_16x16x32_bf16(A0[a], BH0[g], acc[a][g], 0, 0, 0);
#pragma unroll
        for (int a = 0; a < 2; ++a)
#pragma unroll
            for (int g = 0; g < 4; ++g)
                acc[a][g] = __builtin_amdgcn_mfma_f32_16x16x32_bf16(A0[a], BL0[g], acc[a][g], 0, 0, 0);
        int k2 = (k + 2 < 18) ? k + 2 : 16;       // clamped redundant prefetch
        loadA(k2, A0); loadB(k2, BH0, BL0);
#pragma unroll
        for (int a = 0; a < 2; ++a)
#pragma unroll
            for (int g = 0; g < 4; ++g)
                acc[a][g] = __builtin_amdgcn_mfma_f32_16x16x32_bf16(A1[a], BH1[g], acc[a][g], 0, 0, 0);
#pragma unroll
        for (int a = 0; a < 2; ++a)
#pragma unroll
            for (int g = 0; g < 4; ++g)
                acc[a][g] = __builtin_amdgcn_mfma_f32_16x16x32_bf16(A1[a], BL1[g], acc[a][g], 0, 0, 0);
        int k3 = (k + 3 < 18) ? k + 3 : 17;
        loadA(k3, A1); loadB(k3, BH1, BL1);
    }

    // D mapping: col(lane&15)=oc, row=(lane>>4)*4+reg = w-offset
#pragma unroll
    for (int g = 0; g < 4; ++g) {
        const int oc = g * 16 + l15;
        const float bv = bias[oc];
#pragma unroll
        for (int a = 0; a < 2; ++a) {
            const int hr = h0 + 2 * wvi + a;
            float4 st = {acc[a][g].x + bv, acc[a][g].y + bv, acc[a][g].z + bv, acc[a][g].w + bv};
            *reinterpret_cast<float4*>(out + (((long)b * On + oc) * Hn + hr) * Wn + w0 + lg * 4) = st;
        }
    }
}

// ---- exact-zero-weight correction (never taken for Gaussian weights) ----
__global__ void correction_kernel(const float* __restrict__ x, float* __restrict__ hist,
                                  const int* __restrict__ exCnt, const int* __restrict__ exMask) {
    const int c = blockIdx.x;
    const int ec = exCnt[c];
    if (ec == 0) return;
    for (long p = threadIdx.x; p < (long)Bn * Hn * Wn; p += blockDim.x) {
        int b = (int)(p / (Hn * Wn));
        int r = (int)((p / Wn) % Hn);
        int w = (int)(p % Wn);
        unsigned m9 = 0;
        int bit = 0;
        for (int kh = 0; kh < 3; ++kh)
            for (int kw = 0; kw < 3; ++kw, ++bit) {
                int rr = r + kh - 1, ww = w + kw - 1;
                float v = 0.f;
                if ((unsigned)rr < (unsigned)Hn && (unsigned)ww < (unsigned)Wn)
                    v = x[(((long)b * Cn + c) * Hn + rr) * Wn + ww];
                if (v == 0.f) m9 |= 1u << bit;
            }
        for (int e = 0; e < ec; ++e)
            atomicAdd(&hist[c * 10 + __popc(m9 | (unsigned)exMask[c * 64 + e])], 1.0f);
    }
}

// ---------------- fallback (fp32, round-2) — only if ws too small ----------------
namespace fb {
constexpr int TH = 8, TW = 16, CC = 8, NCH = Cn / CC;
constexpr int XROWS = TH + 2, XCOLS = TW + 2, XSTR = 20, WPAD = 68;
}
__global__ void setup_fb_kernel(const float* __restrict__ wt, float* __restrict__ hist,
                                int* __restrict__ n0, int* __restrict__ exCnt,
                                int* __restrict__ exMask) {
    int c = threadIdx.x;
    if (c >= Cn) return;
    int cnt0 = 0, ce = 0;
    for (int oc = 0; oc < On; ++oc) {
        unsigned m = 0;
        const float* wp = wt + (oc * Cn + c) * 9;
        for (int k = 0; k < 9; ++k)
            if (wp[k] == 0.0f) m |= (1u << k);
        if (m == 0u) ++cnt0;
        else exMask[c * 64 + (ce++)] = (int)m;
    }
    n0[c] = cnt0;
    exCnt[c] = ce;
    for (int j = 0; j < 10; ++j) hist[c * 10 + j] = 0.0f;
}
__global__ __launch_bounds__(256, 4) void conv_hist_kernel(
    const float* __restrict__ x, const float* __restrict__ wt,
    const float* __restrict__ bias, float* __restrict__ out,
    float* __restrict__ hist, const int* __restrict__ n0,
    const int* __restrict__ exCnt, const int* __restrict__ exMask)
{
    using namespace fb;
    __shared__ __align__(16) float xs[CC][XROWS][XSTR];
    __shared__ __align__(16) float ws[CC][9][WPAD];
    __shared__ unsigned hist_s[HIST_N];
    const int tid = threadIdx.x;
    const int bx = blockIdx.x;
    const int b = bx / 98;
    const int tt = bx - b * 98;
    const int h0 = (tt / 7) * TH;
    const int w0 = (tt % 7) * TW;
    const int ocg = tid >> 4, pg = tid & 15;
    const int prow = pg >> 1, pcol = (pg & 1) * 8;
    float acc[4][8];
#pragma unroll
    for (int o = 0; o < 4; ++o)
#pragma unroll
        for (int p = 0; p < 8; ++p) acc[o][p] = 0.0f;
    for (int i = tid; i < HIST_N; i += 256) hist_s[i] = 0u;
#pragma unroll 1
    for (int cc = 0; cc < NCH; ++cc) {
        const int cbase = cc * CC;
        __syncthreads();
#pragma unroll 1
        for (int i = tid; i < CC * XROWS * XCOLS; i += 256) {
            int c = i / (XROWS * XCOLS);
            int r = (i - c * XROWS * XCOLS) / XCOLS;
            int cl = i - c * XROWS * XCOLS - r * XCOLS;
            int gr = h0 - 1 + r, gc = w0 - 1 + cl;
            float v = 0.0f;
            if ((unsigned)gr < (unsigned)Hn && (unsigned)gc < (unsigned)Wn)
                v = x[(((long)b * Cn + cbase + c) * Hn + gr) * Wn + gc];
            xs[c][r][cl] = v;
        }
#pragma unroll 1
        for (int i = tid; i < On * CC * 9; i += 256) {
            int oc = i / (CC * 9);
            int j = i - oc * (CC * 9);
            int c = j / 9;
            int k = j - c * 9;
            ws[c][k][oc] = wt[(oc * Cn + cbase + c) * 9 + k];
        }
        __syncthreads();
#pragma unroll 1
        for (int c = 0; c < CC; ++c) {
#pragma unroll
            for (int kh = 0; kh < 3; ++kh) {
                const float* xrow = &xs[c][prow + kh][pcol];
                float4 xa = *(const float4*)xrow;
                float4 xb = *(const float4*)(xrow + 4);
                float2 xc = *(const float2*)(xrow + 8);
                float xr[10] = {xa.x, xa.y, xa.z, xa.w,
                                xb.x, xb.y, xb.z, xb.w, xc.x, xc.y};
#pragma unroll
                for (int kw = 0; kw < 3; ++kw) {
                    float4 wv = *(const float4*)&ws[c][kh * 3 + kw][ocg * 4];
                    float wr[4] = {wv.x, wv.y, wv.z, wv.w};
#pragma unroll
                    for (int o = 0; o < 4; ++o)
#pragma unroll
                        for (int p = 0; p < 8; ++p)
                            acc[o][p] = fmaf(wr[o], xr[p + kw], acc[o][p]);
                }
            }
        }
        if (tid < CC * 16) {
            const int c = tid >> 4;
            const int g = tid & 15;
            const int hr = g >> 1;
            const int hcb = (g & 1) * 8;
            unsigned rm[3];
#pragma unroll
            for (int kh = 0; kh < 3; ++kh) {
                const float* xrow = &xs[c][hr + kh][hcb];
                float4 xa = *(const float4*)xrow;
                float4 xb = *(const float4*)(xrow + 4);
                float2 xc = *(const float2*)(xrow + 8);
                unsigned m = 0;
                m |= (xa.x == 0.0f) ? 1u : 0u;
                m |= (xa.y == 0.0f) ? 2u : 0u;
                m |= (xa.z == 0.0f) ? 4u : 0u;
                m |= (xa.w == 0.0f) ? 8u : 0u;
                m |= (xb.x == 0.0f) ? 16u : 0u;
                m |= (xb.y == 0.0f) ? 32u : 0u;
                m |= (xb.z == 0.0f) ? 64u : 0u;
                m |= (xb.w == 0.0f) ? 128u : 0u;
                m |= (xc.x == 0.0f) ? 256u : 0u;
                m |= (xc.y == 0.0f) ? 512u : 0u;
                rm[kh] = m;
            }
            const int cg = cbase + c;
            const unsigned inc = (unsigned)n0[cg];
            const int ec = exCnt[cg];
#pragma unroll
            for (int j = 0; j < 8; ++j) {
                unsigned m9 = ((rm[0] >> j) & 7u)
                            | (((rm[1] >> j) & 7u) << 3)
                            | (((rm[2] >> j) & 7u) << 6);
                atomicAdd(&hist_s[cg * 10 + __popc(m9)], inc);
                for (int e = 0; e < ec; ++e) {
                    unsigned wz = (unsigned)exMask[cg * 64 + e];
                    atomicAdd(&hist_s[cg * 10 + __popc(m9 | wz)], 1u);
                }
            }
        }
    }
#pragma unroll
    for (int o = 0; o < 4; ++o) {
        const int oc = ocg * 4 + o;
        const float bv = bias[oc];
        float4 v0, v1;
        v0.x = acc[o][0] + bv; v0.y = acc[o][1] + bv;
        v0.z = acc[o][2] + bv; v0.w = acc[o][3] + bv;
        v1.x = acc[o][4] + bv; v1.y = acc[o][5] + bv;
        v1.z = acc[o][6] + bv; v1.w = acc[o][7] + bv;
        float* dst = &out[(((long)b * On + oc) * Hn + (h0 + prow)) * Wn + w0 + pcol];
        *(float4*)dst = v0;
        *(float4*)(dst + 4) = v1;
    }
    __syncthreads();
    for (int i = tid; i < HIST_N; i += 256)
        atomicAdd(&hist[i], (float)hist_s[i]);
}

// ---------------- host ----------------
extern "C" void kernel_launch(void* const* d_in, const int* in_sizes, int n_in,
                              void* d_out, int out_size, void* d_ws, size_t ws_size,
                              hipStream_t stream) {
    const float* x    = (const float*)d_in[0];
    const float* wt   = (const float*)d_in[1];
    const float* bias = (const float*)d_in[2];
    float* out  = (float*)d_out;
    float* hist = out + CONV_ELEMS;

    int* n0     = (int*)d_ws;
    int* exCnt  = n0 + 64;
    int* exMask = n0 + 128;       // 64*64 ints, ends at 16896 B < META_BYTES

    if (ws_size >= NEED_WS) {
        ushort* xh = (ushort*)((char*)d_ws + META_BYTES);
        ushort* wb = xh + XT_ELEMS;
        prep_wsetup_kernel<<<Cn, 64, 0, stream>>>(wt, wb, hist, n0, exCnt, exMask);
        prep_x_kernel<<<INT_BLOCKS + HALO_BLOCKS, 256, 0, stream>>>(x, xh);
        hist_kernel<<<Bn * Cn, 256, 0, stream>>>(x, hist, n0);
        conv_mfma_kernel<<<Bn * 98, 256, 0, stream>>>(xh, wb, bias, out);
        correction_kernel<<<Cn, 256, 0, stream>>>(x, hist, exCnt, exMask);
    } else {
        setup_fb_kernel<<<1, 64, 0, stream>>>(wt, hist, n0, exCnt, exMask);
        conv_hist_kernel<<<Bn * 98, 256, 0, stream>>>(x, wt, bias, out, hist,
                                                      n0, exCnt, exMask);
    }
}

// Round 5
// 104.073 us; speedup vs baseline: 5.2719x; 1.3602x over previous
//
#include <hip/hip_runtime.h>

typedef __attribute__((ext_vector_type(8))) short bf16x8;
typedef __attribute__((ext_vector_type(4))) float f32x4;

namespace {
constexpr int Bn = 8, Cn = 64, On = 64, Hn = 112, Wn = 112;
constexpr long CONV_ELEMS = (long)Bn * On * Hn * Wn;     // 6422528
constexpr int HP = 114, WP = 114;                        // padded dims (halo)
constexpr long XT_ELEMS = (long)Bn * HP * WP * Cn;       // 6653952
constexpr int WB_PER_OC = 1152;                          // hi 576 + lo 576
constexpr size_t META_BYTES = 17408;
constexpr size_t NEED_WS = META_BYTES + (size_t)XT_ELEMS * 2 + (size_t)On * WB_PER_OC * 2;
constexpr int HIST_N = Cn * 10;
constexpr int HALO_PER_B = 2 * WP * Cn + 2 * Hn * Cn;    // 28928
constexpr int HALO_ELEMS = Bn * HALO_PER_B;              // 231424
constexpr int INT_BLOCKS = Bn * Hn * 2;                  // 1792
constexpr int HALO_BLOCKS = (HALO_ELEMS + 255) / 256;    // 904
}

__device__ __forceinline__ ushort f2bf(float v) {        // RNE float->bf16 bits
    unsigned u = __float_as_uint(v);
    return (ushort)((u + 0x7fffu + ((u >> 16) & 1u)) >> 16);
}
__device__ __forceinline__ float bf2f(ushort b) {
    return __uint_as_float(((unsigned)b) << 16);
}

// ---- weights -> wb[oc][k] (k = kp*64+c), hi|lo; zero-weight bookkeeping; hist zero ----
__global__ void prep_wsetup_kernel(const float* __restrict__ wt, ushort* __restrict__ wb,
                                   float* __restrict__ hist, int* __restrict__ n0,
                                   int* __restrict__ exCnt, int* __restrict__ exMask) {
    __shared__ int ecnt;
    const int c = blockIdx.x;      // 64 blocks
    const int oc = threadIdx.x;    // 64 threads = 1 wave
    if (oc == 0) ecnt = 0;
    __syncthreads();
    const float* wp = wt + (oc * Cn + c) * 9;
    unsigned m = 0;
    float wv[9];
#pragma unroll
    for (int k = 0; k < 9; ++k) {
        wv[k] = wp[k];
        if (wv[k] == 0.0f) m |= 1u << k;
    }
#pragma unroll
    for (int kp = 0; kp < 9; ++kp) {
        ushort hi = f2bf(wv[kp]);
        ushort lo = f2bf(wv[kp] - bf2f(hi));
        wb[oc * WB_PER_OC + kp * 64 + c] = hi;
        wb[oc * WB_PER_OC + 576 + kp * 64 + c] = lo;
    }
    unsigned long long zb = __ballot(m == 0u);
    if (m != 0u) {
        int slot = atomicAdd(&ecnt, 1);
        exMask[c * 64 + slot] = (int)m;
    }
    __syncthreads();
    if (oc == 0) { n0[c] = __popcll(zb); exCnt[c] = ecnt; }
    if (c == 0) for (int i = oc; i < HIST_N; i += 64) hist[i] = 0.0f;
}

// ---- x (NCHW fp32) -> xh [b][h+1][w+1][c] bf16; halo-zero fused via extra blocks ----
__global__ __launch_bounds__(256) void prep_x_kernel(
    const float* __restrict__ x, ushort* __restrict__ xh) {
    const int bx = blockIdx.x;
    const int tid = threadIdx.x;
    if (bx >= INT_BLOCKS) {                       // halo-zero blocks
        int idx = (bx - INT_BLOCKS) * 256 + tid;
        if (idx < HALO_ELEMS) {
            int b = idx / HALO_PER_B;
            int r = idx - b * HALO_PER_B;
            int h, w, cc;
            if (r < WP * Cn)                    { h = 0;      w = r / Cn;               cc = r & 63; }
            else if (r < 2 * WP * Cn)           { int q = r - WP * Cn; h = HP - 1; w = q / Cn; cc = q & 63; }
            else if (r < 2 * WP * Cn + Hn * Cn) { int q = r - 2 * WP * Cn; h = 1 + q / Cn; w = 0; cc = q & 63; }
            else                                { int q = r - 2 * WP * Cn - Hn * Cn; h = 1 + q / Cn; w = WP - 1; cc = q & 63; }
            xh[((long)(b * HP + h) * WP + w) * 64 + cc] = 0;
        }
        return;
    }
    __shared__ float ls[64][57];
    const int b = bx / 224;
    const int rem = bx - b * 224;
    const int h = rem >> 1;
    const int w0 = (rem & 1) * 56;
    for (int i = tid; i < 64 * 56; i += 256) {
        int c = i / 56, w = i - c * 56;
        ls[c][w] = x[(((long)b * Cn + c) * Hn + h) * Wn + w0 + w];
    }
    __syncthreads();
    for (int i = tid; i < 56 * 64; i += 256) {
        int w = i >> 6, c = i & 63;
        xh[(((long)b * HP + h + 1) * WP + (w0 + w + 1)) * 64 + c] = f2bf(ls[c][w]);
    }
}

// ---- hist: per-(b,c) plane; ballot row-masks + 3-row popc windows; correction folded ----
__global__ __launch_bounds__(256) void hist_kernel(
    const float* __restrict__ x, float* __restrict__ hist, const int* __restrict__ n0,
    const int* __restrict__ exCnt, const int* __restrict__ exMask) {
    __shared__ unsigned long long zr[HP][2];      // 114-bit row masks, rows -1..112
    __shared__ unsigned hcnt[10];
    const int tid = threadIdx.x;
    const int lane = tid & 63, wv = tid >> 6;
    const int b = blockIdx.x >> 6;
    const int c = blockIdx.x & 63;
    if (tid < 10) hcnt[tid] = 0u;
    if (tid < 2) { zr[tid * (HP - 1)][0] = ~0ull; zr[tid * (HP - 1)][1] = ~0ull; }
    const float* xp = x + ((long)b * Cn + c) * (Hn * Wn);
    // phase 1: one ballot per 64-px chunk builds the row zero-mask
    for (int r = wv; r < Hn; r += 4) {
        float v0 = xp[r * Wn + lane];
        float v1 = (lane < 48) ? xp[r * Wn + 64 + lane] : 1.0f;
        unsigned long long mA = __ballot(v0 == 0.0f);
        unsigned long long mB = __ballot(v1 == 0.0f);
        if (lane == 0) {                          // bit j = (col j-1 == 0); pads at 0,113
            zr[r + 1][0] = (mA << 1) | 1ull;
            zr[r + 1][1] = (mA >> 63) | (mB << 1) | (1ull << 49);
        }
    }
    __syncthreads();
    // phase 2: 2 threads per row, 56 px each, 6-bit packed bins
    if (tid < 224) {
        const int r = tid >> 1, half = tid & 1;
        unsigned long long t0 = zr[r][0],     t1 = zr[r][1];
        unsigned long long m0 = zr[r + 1][0], m1 = zr[r + 1][1];
        unsigned long long b0 = zr[r + 2][0], b1 = zr[r + 2][1];
        unsigned long long T, M, B2;
        if (half == 0) { T = t0; M = m0; B2 = b0; }
        else { T = (t0 >> 56) | (t1 << 8); M = (m0 >> 56) | (m1 << 8); B2 = (b0 >> 56) | (b1 << 8); }
        unsigned pk0 = 0, pk1 = 0;                // bins 0..4 / 5..9, 6 bits each (max 56)
        for (int w = 0; w < 56; ++w) {
            int z = __popc((unsigned)(T >> w) & 7u) + __popc((unsigned)(M >> w) & 7u)
                  + __popc((unsigned)(B2 >> w) & 7u);
            if (z < 5) pk0 += 1u << (6 * z); else pk1 += 1u << (6 * (z - 5));
        }
#pragma unroll
        for (int j = 0; j < 5; ++j) {
            atomicAdd(&hcnt[j],     (pk0 >> (6 * j)) & 63u);
            atomicAdd(&hcnt[5 + j], (pk1 >> (6 * j)) & 63u);
        }
        // exact-zero-weight correction (never taken for Gaussian weights)
        const int ec = exCnt[c];
        if (ec > 0) {
            for (int w = 0; w < 56; ++w) {
                unsigned m9 = ((unsigned)(T >> w) & 7u)
                            | (((unsigned)(M >> w) & 7u) << 3)
                            | (((unsigned)(B2 >> w) & 7u) << 6);
                for (int e = 0; e < ec; ++e)
                    atomicAdd(&hist[c * 10 + __popc(m9 | (unsigned)exMask[c * 64 + e])], 1.0f);
            }
        }
    }
    __syncthreads();
    if (tid < 10)
        atomicAdd(&hist[c * 10 + tid], (float)(hcnt[tid] * (unsigned)n0[c]));
}

// ---- conv: wave = 128px x 16oc, B (hi+lo, full K) RESIDENT in 144 VGPRs ----
// k-loop has ZERO weight loads: 8 coalesced A loads + 16 MFMAs per k-step.
__global__ __launch_bounds__(256, 2) void conv_mfma_kernel(
    const ushort* __restrict__ xh, const ushort* __restrict__ wb,
    const float* __restrict__ bias, float* __restrict__ out)
{
    int bid = (int)blockIdx.x;
    bid = (bid & 7) * 98 + (bid >> 3);            // XCD swizzle: one image per XCD
    const int b = bid / 98;
    const int t = bid - b * 98;
    const int h0 = (t / 7) * 8, w0 = (t % 7) * 16;
    const int tid = threadIdx.x;
    const int lane = tid & 63, wvi = tid >> 6;    // wave wvi owns oc [16*wvi, 16*wvi+16)
    const int l15 = lane & 15, lg = lane >> 4;

    // B preload: once per wave (36 gathers), amortized over 288 MFMAs
    bf16x8 BH[18], BL[18];
    const ushort* Bw = wb + (wvi * 16 + l15) * WB_PER_OC + 8 * lg;
#pragma unroll
    for (int k = 0; k < 18; ++k) {
        BH[k] = *(const bf16x8*)(Bw + k * 32);
        BL[k] = *(const bf16x8*)(Bw + 576 + k * 32);
    }

    f32x4 acc[8];
#pragma unroll
    for (int a = 0; a < 8; ++a) acc[a] = (f32x4){0.f, 0.f, 0.f, 0.f};

    const ushort* As = xh + ((long)((b * HP + h0) * WP + w0 + l15) * 64 + 8 * lg);

#pragma unroll
    for (int k = 0; k < 18; ++k) {                // fully unrolled: static BH/BL indices
        const int kp = k >> 1, ch = k & 1;
        const int dh = kp / 3, dw = kp - 3 * dh;
        const int off = (dh * WP + dw) * 64 + 32 * ch;
        bf16x8 A[8];
#pragma unroll
        for (int a = 0; a < 8; ++a)
            A[a] = *(const bf16x8*)(As + off + a * (WP * 64));
#pragma unroll
        for (int a = 0; a < 8; ++a)
            acc[a] = __builtin_amdgcn_mfma_f32_16x16x32_bf16(A[a], BH[k], acc[a], 0, 0, 0);
#pragma unroll
        for (int a = 0; a < 8; ++a)
            acc[a] = __builtin_amdgcn_mfma_f32_16x16x32_bf16(A[a], BL[k], acc[a], 0, 0, 0);
    }

    // D mapping: col(lane&15)=oc-within-frag, row=(lane>>4)*4+reg = w-offset
    const int oc = wvi * 16 + l15;
    const float bv = bias[oc];
#pragma unroll
    for (int a = 0; a < 8; ++a) {
        float4 st = {acc[a].x + bv, acc[a].y + bv, acc[a].z + bv, acc[a].w + bv};
        *reinterpret_cast<float4*>(
            out + (((long)b * On + oc) * Hn + h0 + a) * Wn + w0 + lg * 4) = st;
    }
}

// ---------------- fallback (fp32, round-2) — only if ws too small ----------------
namespace fb {
constexpr int TH = 8, TW = 16, CC = 8, NCH = Cn / CC;
constexpr int XROWS = TH + 2, XCOLS = TW + 2, XSTR = 20, WPAD = 68;
}
__global__ void setup_fb_kernel(const float* __restrict__ wt, float* __restrict__ hist,
                                int* __restrict__ n0, int* __restrict__ exCnt,
                                int* __restrict__ exMask) {
    int c = threadIdx.x;
    if (c >= Cn) return;
    int cnt0 = 0, ce = 0;
    for (int oc = 0; oc < On; ++oc) {
        unsigned m = 0;
        const float* wp = wt + (oc * Cn + c) * 9;
        for (int k = 0; k < 9; ++k)
            if (wp[k] == 0.0f) m |= (1u << k);
        if (m == 0u) ++cnt0;
        else exMask[c * 64 + (ce++)] = (int)m;
    }
    n0[c] = cnt0;
    exCnt[c] = ce;
    for (int j = 0; j < 10; ++j) hist[c * 10 + j] = 0.0f;
}
__global__ __launch_bounds__(256, 4) void conv_hist_kernel(
    const float* __restrict__ x, const float* __restrict__ wt,
    const float* __restrict__ bias, float* __restrict__ out,
    float* __restrict__ hist, const int* __restrict__ n0,
    const int* __restrict__ exCnt, const int* __restrict__ exMask)
{
    using namespace fb;
    __shared__ __align__(16) float xs[CC][XROWS][XSTR];
    __shared__ __align__(16) float ws[CC][9][WPAD];
    __shared__ unsigned hist_s[HIST_N];
    const int tid = threadIdx.x;
    const int bx = blockIdx.x;
    const int b = bx / 98;
    const int tt = bx - b * 98;
    const int h0 = (tt / 7) * TH;
    const int w0 = (tt % 7) * TW;
    const int ocg = tid >> 4, pg = tid & 15;
    const int prow = pg >> 1, pcol = (pg & 1) * 8;
    float acc[4][8];
#pragma unroll
    for (int o = 0; o < 4; ++o)
#pragma unroll
        for (int p = 0; p < 8; ++p) acc[o][p] = 0.0f;
    for (int i = tid; i < HIST_N; i += 256) hist_s[i] = 0u;
#pragma unroll 1
    for (int cc = 0; cc < NCH; ++cc) {
        const int cbase = cc * CC;
        __syncthreads();
#pragma unroll 1
        for (int i = tid; i < CC * XROWS * XCOLS; i += 256) {
            int c = i / (XROWS * XCOLS);
            int r = (i - c * XROWS * XCOLS) / XCOLS;
            int cl = i - c * XROWS * XCOLS - r * XCOLS;
            int gr = h0 - 1 + r, gc = w0 - 1 + cl;
            float v = 0.0f;
            if ((unsigned)gr < (unsigned)Hn && (unsigned)gc < (unsigned)Wn)
                v = x[(((long)b * Cn + cbase + c) * Hn + gr) * Wn + gc];
            xs[c][r][cl] = v;
        }
#pragma unroll 1
        for (int i = tid; i < On * CC * 9; i += 256) {
            int oc = i / (CC * 9);
            int j = i - oc * (CC * 9);
            int c = j / 9;
            int k = j - c * 9;
            ws[c][k][oc] = wt[(oc * Cn + cbase + c) * 9 + k];
        }
        __syncthreads();
#pragma unroll 1
        for (int c = 0; c < CC; ++c) {
#pragma unroll
            for (int kh = 0; kh < 3; ++kh) {
                const float* xrow = &xs[c][prow + kh][pcol];
                float4 xa = *(const float4*)xrow;
                float4 xb = *(const float4*)(xrow + 4);
                float2 xc = *(const float2*)(xrow + 8);
                float xr[10] = {xa.x, xa.y, xa.z, xa.w,
                                xb.x, xb.y, xb.z, xb.w, xc.x, xc.y};
#pragma unroll
                for (int kw = 0; kw < 3; ++kw) {
                    float4 wv = *(const float4*)&ws[c][kh * 3 + kw][ocg * 4];
                    float wr[4] = {wv.x, wv.y, wv.z, wv.w};
#pragma unroll
                    for (int o = 0; o < 4; ++o)
#pragma unroll
                        for (int p = 0; p < 8; ++p)
                            acc[o][p] = fmaf(wr[o], xr[p + kw], acc[o][p]);
                }
            }
        }
        if (tid < CC * 16) {
            const int c = tid >> 4;
            const int g = tid & 15;
            const int hr = g >> 1;
            const int hcb = (g & 1) * 8;
            unsigned rm[3];
#pragma unroll
            for (int kh = 0; kh < 3; ++kh) {
                const float* xrow = &xs[c][hr + kh][hcb];
                float4 xa = *(const float4*)xrow;
                float4 xb = *(const float4*)(xrow + 4);
                float2 xc = *(const float2*)(xrow + 8);
                unsigned m = 0;
                m |= (xa.x == 0.0f) ? 1u : 0u;
                m |= (xa.y == 0.0f) ? 2u : 0u;
                m |= (xa.z == 0.0f) ? 4u : 0u;
                m |= (xa.w == 0.0f) ? 8u : 0u;
                m |= (xb.x == 0.0f) ? 16u : 0u;
                m |= (xb.y == 0.0f) ? 32u : 0u;
                m |= (xb.z == 0.0f) ? 64u : 0u;
                m |= (xb.w == 0.0f) ? 128u : 0u;
                m |= (xc.x == 0.0f) ? 256u : 0u;
                m |= (xc.y == 0.0f) ? 512u : 0u;
                rm[kh] = m;
            }
            const int cg = cbase + c;
            const unsigned inc = (unsigned)n0[cg];
            const int ec = exCnt[cg];
#pragma unroll
            for (int j = 0; j < 8; ++j) {
                unsigned m9 = ((rm[0] >> j) & 7u)
                            | (((rm[1] >> j) & 7u) << 3)
                            | (((rm[2] >> j) & 7u) << 6);
                atomicAdd(&hist_s[cg * 10 + __popc(m9)], inc);
                for (int e = 0; e < ec; ++e) {
                    unsigned wz = (unsigned)exMask[cg * 64 + e];
                    atomicAdd(&hist_s[cg * 10 + __popc(m9 | wz)], 1u);
                }
            }
        }
    }
#pragma unroll
    for (int o = 0; o < 4; ++o) {
        const int oc = ocg * 4 + o;
        const float bv = bias[oc];
        float4 v0, v1;
        v0.x = acc[o][0] + bv; v0.y = acc[o][1] + bv;
        v0.z = acc[o][2] + bv; v0.w = acc[o][3] + bv;
        v1.x = acc[o][4] + bv; v1.y = acc[o][5] + bv;
        v1.z = acc[o][6] + bv; v1.w = acc[o][7] + bv;
        float* dst = &out[(((long)b * On + oc) * Hn + (h0 + prow)) * Wn + w0 + pcol];
        *(float4*)dst = v0;
        *(float4*)(dst + 4) = v1;
    }
    __syncthreads();
    for (int i = tid; i < HIST_N; i += 256)
        atomicAdd(&hist[i], (float)hist_s[i]);
}

// ---------------- host ----------------
extern "C" void kernel_launch(void* const* d_in, const int* in_sizes, int n_in,
                              void* d_out, int out_size, void* d_ws, size_t ws_size,
                              hipStream_t stream) {
    const float* x    = (const float*)d_in[0];
    const float* wt   = (const float*)d_in[1];
    const float* bias = (const float*)d_in[2];
    float* out  = (float*)d_out;
    float* hist = out + CONV_ELEMS;

    int* n0     = (int*)d_ws;
    int* exCnt  = n0 + 64;
    int* exMask = n0 + 128;       // 64*64 ints, ends at 16896 B < META_BYTES

    if (ws_size >= NEED_WS) {
        ushort* xh = (ushort*)((char*)d_ws + META_BYTES);
        ushort* wb = xh + XT_ELEMS;
        prep_wsetup_kernel<<<Cn, 64, 0, stream>>>(wt, wb, hist, n0, exCnt, exMask);
        prep_x_kernel<<<INT_BLOCKS + HALO_BLOCKS, 256, 0, stream>>>(x, xh);
        hist_kernel<<<Bn * Cn, 256, 0, stream>>>(x, hist, n0, exCnt, exMask);
        conv_mfma_kernel<<<Bn * 98, 256, 0, stream>>>(xh, wb, bias, out);
    } else {
        setup_fb_kernel<<<1, 64, 0, stream>>>(wt, hist, n0, exCnt, exMask);
        conv_hist_kernel<<<Bn * 98, 256, 0, stream>>>(x, wt, bias, out, hist,
                                                      n0, exCnt, exMask);
    }
}